// Round 1
// baseline (376.865 us; speedup 1.0000x reference)
//
#include <hip/hip_runtime.h>
#include <math.h>

#define B_   8
#define N_   6
#define D_   41
#define C_   64
#define FH_  16
#define FW_  44
#define HW_  (FH_*FW_)          // 704
#define CHW_ ((D_+C_)*FH_*FW_)  // 73920
#define NPIX (B_*N_*FH_*FW_)    // 33792
#define NXV  200
#define NYV  200

// exact-rounding helpers: prevent FMA contraction / reassociation
__device__ __forceinline__ float mul_(float a, float b){ return __fmul_rn(a,b); }
__device__ __forceinline__ float add_(float a, float b){ return __fadd_rn(a,b); }
__device__ __forceinline__ float sub_(float a, float b){ return __fsub_rn(a,b); }

// 3x3 inverse mirroring LAPACK getrf (partial pivot) + getrs with unit-L /
// upper triangular solves using divisions (jax: inv(a) == solve(a, eye)).
__device__ void inv3(const float* A, float* X){
  float U[3][3];
  float L[3][3] = {{1.f,0.f,0.f},{0.f,1.f,0.f},{0.f,0.f,1.f}};
  int p[3] = {0,1,2};
  #pragma unroll
  for (int i=0;i<3;i++)
    #pragma unroll
    for (int j=0;j<3;j++) U[i][j] = A[i*3+j];
  #pragma unroll
  for (int k=0;k<3;k++){
    int pr = k; float mx = fabsf(U[k][k]);
    #pragma unroll
    for (int r=0;r<3;r++){
      if (r > k){ float v = fabsf(U[r][k]); if (v > mx){ mx = v; pr = r; } }
    }
    if (pr != k){
      #pragma unroll
      for (int j=0;j<3;j++){ float t=U[k][j]; U[k][j]=U[pr][j]; U[pr][j]=t; }
      #pragma unroll
      for (int j=0;j<3;j++){ if (j<k){ float t=L[k][j]; L[k][j]=L[pr][j]; L[pr][j]=t; } }
      int t=p[k]; p[k]=p[pr]; p[pr]=t;
    }
    #pragma unroll
    for (int r=0;r<3;r++){
      if (r > k){
        float m = __fdiv_rn(U[r][k], U[k][k]);
        L[r][k] = m;
        #pragma unroll
        for (int j=0;j<3;j++){ if (j>k) U[r][j] = sub_(U[r][j], mul_(m, U[k][j])); }
      }
    }
  }
  #pragma unroll
  for (int col=0; col<3; col++){
    float y[3];
    #pragma unroll
    for (int i=0;i<3;i++) y[i] = (p[i]==col) ? 1.f : 0.f;
    // forward solve (unit lower)
    #pragma unroll
    for (int i=1;i<3;i++)
      #pragma unroll
      for (int j=0;j<3;j++){ if (j<i) y[i] = sub_(y[i], mul_(L[i][j], y[j])); }
    // back solve (upper, with division)
    float x[3];
    #pragma unroll
    for (int i=2;i>=0;i--){
      float t = y[i];
      #pragma unroll
      for (int j=0;j<3;j++){ if (j>i) t = sub_(t, mul_(U[i][j], x[j])); }
      x[i] = __fdiv_rn(t, U[i][i]);
    }
    X[0*3+col]=x[0]; X[1*3+col]=x[1]; X[2*3+col]=x[2];
  }
}

// per-(b,n) params: invPost(9), M = rots@inv(intrins) (9), post_trans(3), trans(3)
__global__ void lss_prep(const float* __restrict__ rots, const float* __restrict__ trans,
                         const float* __restrict__ intrins, const float* __restrict__ post_rots,
                         const float* __restrict__ post_trans, float* __restrict__ cam){
  int t = threadIdx.x;
  if (t >= B_*N_) return;
  float invK[9], invP[9];
  inv3(intrins + t*9, invK);
  inv3(post_rots + t*9, invP);
  const float* R = rots + t*9;
  float M[9];
  #pragma unroll
  for (int i=0;i<3;i++)
    #pragma unroll
    for (int j=0;j<3;j++){
      // plain mul+add, ascending k (no FMA)
      float s = mul_(R[i*3+0], invK[0*3+j]);
      s = add_(s, mul_(R[i*3+1], invK[1*3+j]));
      s = add_(s, mul_(R[i*3+2], invK[2*3+j]));
      M[i*3+j] = s;
    }
  float* o = cam + t*24;
  #pragma unroll
  for (int i=0;i<9;i++) o[i] = invP[i];
  #pragma unroll
  for (int i=0;i<9;i++) o[9+i] = M[i];
  o[18]=post_trans[t*3+0]; o[19]=post_trans[t*3+1]; o[20]=post_trans[t*3+2];
  o[21]=trans[t*3+0];      o[22]=trans[t*3+1];      o[23]=trans[t*3+2];
}

// one wave per pixel; lane = channel; loop over depth bins
__global__ __launch_bounds__(256) void lss_scatter(const float* __restrict__ feat,
    const float* __restrict__ cam, float* __restrict__ pooled, int staged){
  int wave = threadIdx.x >> 6, lane = threadIdx.x & 63;
  int pix = blockIdx.x*4 + wave;
  if (pix >= NPIX) return;
  int w = pix % FW_; int t = pix / FW_;
  int h = t % FH_;   t /= FH_;
  int n = t % N_;    int b = t / N_;

  const float* cp = cam + (b*N_+n)*24;
  const float* fb = feat + (size_t)(b*N_+n)*CHW_ + h*FW_ + w;

  // softmax over D depth logits (wave-parallel)
  float logit = (lane < D_) ? fb[(size_t)lane*HW_] : -INFINITY;
  float mx = logit;
  #pragma unroll
  for (int o=32;o;o>>=1) mx = fmaxf(mx, __shfl_xor(mx,o));
  float e = (lane < D_) ? expf(logit - mx) : 0.f;
  float ssum = e;
  #pragma unroll
  for (int o=32;o;o>>=1) ssum += __shfl_xor(ssum,o);
  float dprob = e / ssum;

  float fc = fb[(size_t)(D_+lane)*HW_];   // this lane's channel feature

  const float ip00=cp[0],ip01=cp[1],ip02=cp[2],ip10=cp[3],ip11=cp[4],ip12=cp[5],
              ip20=cp[6],ip21=cp[7],ip22=cp[8];
  const float m00=cp[9], m01=cp[10], m02=cp[11], m10=cp[12], m11=cp[13], m12=cp[14],
              m20=cp[15], m21=cp[16], m22=cp[17];
  const float ptx=cp[18], pty=cp[19], ptz=cp[20], trx=cp[21], try_=cp[22], trz=cp[23];

  // frustum (jax linspace f32: 0 + fl(703/43)*w ; 17*h ; 4+d)
  float u = mul_((float)w, 703.0f/43.0f);
  float v = mul_((float)h, 17.0f);
  float p0 = sub_(u, ptx);
  float p1 = sub_(v, pty);
  // partial inv(post_rots) matvec: first two terms, left-assoc
  float a0 = add_(mul_(ip00,p0), mul_(ip01,p1));
  float a1 = add_(mul_(ip10,p0), mul_(ip11,p1));
  float a2 = add_(mul_(ip20,p0), mul_(ip21,p1));

  for (int d=0; d<D_; d++){
    float dd = add_(4.0f, (float)d);
    float p2 = sub_(dd, ptz);
    float r0 = add_(a0, mul_(ip02,p2));
    float r1 = add_(a1, mul_(ip12,p2));
    float r2 = add_(a2, mul_(ip22,p2));
    // unproject
    float q0 = mul_(r0, r2);
    float q1 = mul_(r1, r2);
    float q2 = r2;
    // geom = M @ q + trans  (plain mul+add ascending k, then + trans)
    float g0 = add_(add_(add_(mul_(m00,q0), mul_(m01,q1)), mul_(m02,q2)), trx);
    float g1 = add_(add_(add_(mul_(m10,q0), mul_(m11,q1)), mul_(m12,q2)), try_);
    float g2 = add_(add_(add_(mul_(m20,q0), mul_(m21,q1)), mul_(m22,q2)), trz);
    // voxelize: (geom - (bx - dx/2)) / dx, trunc toward zero
    float bxq = mul_(sub_(g0, -50.0f), 2.0f);     // /0.5 == *2 exactly
    float byq = mul_(sub_(g1, -50.0f), 2.0f);
    float bzq = __fdiv_rn(sub_(g2, -10.0f), 20.0f);
    int gx = (int)bxq, gy = (int)byq, gz = (int)bzq;
    bool kept = (gx>=0) & (gx<NXV) & (gy>=0) & (gy<NYV) & (gz==0);
    if (kept){
      float dp  = __shfl(dprob, d);
      float val = mul_(dp, fc);
      if (staged) atomicAdd(&pooled[(((size_t)b*NXV + gx)*NYV + gy)*C_ + lane], val);
      else        atomicAdd(&pooled[(((size_t)b*C_ + lane)*NXV + gx)*NYV + gy], val);
    }
  }
}

// pooled[b][x][y][c] -> out[b][c][x][y], LDS-tiled for coalescing both sides
__global__ __launch_bounds__(256) void lss_transpose(const float* __restrict__ pooled,
                                                     float* __restrict__ out){
  __shared__ float lds[64][65];
  int bid  = blockIdx.x;          // ((b*200)+x)*4 + tile
  int tile = bid & 3;
  int x    = (bid >> 2) % NXV;
  int b    = bid / (NXV*4);
  int y0   = tile*64;
  int tc = threadIdx.x & 63, tr = threadIdx.x >> 6;   // tr in 0..3
  #pragma unroll
  for (int yy=tr; yy<64; yy+=4){
    int y = y0 + yy;
    if (y < NYV) lds[yy][tc] = pooled[(((size_t)b*NXV + x)*NYV + y)*C_ + tc];
  }
  __syncthreads();
  int y = y0 + tc;
  if (y < NYV){
    #pragma unroll
    for (int cc=tr; cc<64; cc+=4){
      out[(((size_t)(b*C_ + cc))*NXV + x)*NYV + y] = lds[tc][cc];
    }
  }
}

extern "C" void kernel_launch(void* const* d_in, const int* in_sizes, int n_in,
                              void* d_out, int out_size, void* d_ws, size_t ws_size,
                              hipStream_t stream) {
  const float* feat       = (const float*)d_in[0];
  const float* rots       = (const float*)d_in[1];
  const float* trans      = (const float*)d_in[2];
  const float* intrins    = (const float*)d_in[3];
  const float* post_rots  = (const float*)d_in[4];
  const float* post_trans = (const float*)d_in[5];
  float* out = (float*)d_out;

  const size_t pooledBytes = (size_t)B_*NXV*NYV*C_*sizeof(float);  // 81.92 MB
  const size_t camBytes    = (size_t)B_*N_*24*sizeof(float);       // 4.6 KB
  bool staged = ws_size >= pooledBytes + camBytes;

  float* cam;
  float* pooled;
  if (staged){
    pooled = (float*)d_ws;
    cam    = (float*)((char*)d_ws + pooledBytes);
    hipMemsetAsync(d_ws, 0, pooledBytes, stream);
  } else {
    cam    = (float*)d_ws;           // needs >= 4.6 KB of scratch
    pooled = out;
    hipMemsetAsync(d_out, 0, (size_t)out_size*sizeof(float), stream);
  }

  lss_prep<<<1, 64, 0, stream>>>(rots, trans, intrins, post_rots, post_trans, cam);
  lss_scatter<<<NPIX/4, 256, 0, stream>>>(feat, cam, pooled, staged ? 1 : 0);
  if (staged) lss_transpose<<<B_*NXV*4, 256, 0, stream>>>(pooled, out);
}